// Round 2
// baseline (2115.621 us; speedup 1.0000x reference)
//
#include <hip/hip_runtime.h>

// ---------------------------------------------------------------------------
// 2-layer LSTM (B=64, T=256, D=512, H1=H2=1024) + dense head.
// R9: R8's K-sub-tile pipeline, but with LIGHT barriers between sub-tiles.
// R8 (2114us, regression): the 3 extra __syncthreads each compile to
// s_waitcnt vmcnt(0) lgkmcnt(0) + s_barrier -> drained the depth-16 load
// ring (incl. prefetched future chunks) before every MFMA phase. Overlap
// became serialization. Fix (T3+T4 pattern): inter-sub-tile sync is
// "s_waitcnt lgkmcnt(0); s_barrier" only -- each wave's ds_writes are
// complete (cross-wave LDS visibility), while global loads stay in flight
// ACROSS the barrier. vmcnt(N) stays counted, never 0, inside the step;
// h-stores drain only at the grid barrier (staging done by then).
// ---------------------------------------------------------------------------

typedef __bf16 bf16x8 __attribute__((ext_vector_type(8)));
typedef float f32x4 __attribute__((ext_vector_type(4)));
typedef unsigned int u32x4 __attribute__((ext_vector_type(4)));
typedef unsigned short u16;

#define LDS_Z_OFF 131584   // Alds worst: 32*(2048+8)*2 = 131584 B
#define LDS_TOTAL 140288   // + Zlds 32*68*4 = 8704 B

__device__ __forceinline__ u16 f2bf(float f) {
  unsigned u = __float_as_uint(f);
  unsigned r = (u + 0x7FFFu + ((u >> 16) & 1u)) >> 16;  // RNE (finite inputs)
  return (u16)r;
}

// LDS-only barrier: waits own ds ops, does NOT drain vmcnt -> global loads
// stay in flight across it (T4). "memory" clobber pins ordering for codegen.
__device__ __forceinline__ void sync_lds_only() {
  asm volatile("s_waitcnt lgkmcnt(0)\n\ts_barrier" ::: "memory");
}

// in: fp32 [R][C] row-major  ->  out: bf16 [C][R] row-major (i.e. B^T layout)
__global__ __launch_bounds__(256) void transpose_to_bf16(
    const float* __restrict__ in, u16* __restrict__ out, int R, int C) {
  __shared__ float tile[32][33];
  int tx = threadIdx.x & 31, ty = threadIdx.x >> 5;  // 32 x 8
  int c0 = blockIdx.x * 32, r0 = blockIdx.y * 32;
#pragma unroll
  for (int i = 0; i < 4; ++i)
    tile[ty + i * 8][tx] = in[(size_t)(r0 + ty + i * 8) * C + (c0 + tx)];
  __syncthreads();
#pragma unroll
  for (int i = 0; i < 4; ++i)
    out[(size_t)(c0 + ty + i * 8) * R + (r0 + tx)] = f2bf(tile[tx][ty + i * 8]);
}

__global__ __launch_bounds__(256) void convert_to_bf16(
    const float* __restrict__ in, u16* __restrict__ out, int n4) {
  int i = blockIdx.x * 256 + threadIdx.x;
  if (i >= n4) return;
  float4 v = reinterpret_cast<const float4*>(in)[i];
  ushort4 o;
  o.x = f2bf(v.x); o.y = f2bf(v.y); o.z = f2bf(v.z); o.w = f2bf(v.w);
  reinterpret_cast<ushort4*>(out)[i] = o;
}

__global__ void init_bar(unsigned* __restrict__ bar) { bar[threadIdx.x] = 0u; }

__device__ __forceinline__ void store_h_sc1(u16* p, unsigned v) {
  asm volatile("global_store_short %0, %1, off sc1" :: "v"(p), "v"(v) : "memory");
}

// ---- A-staging: sc1/cached loads -> LDS via depth-16 ring, manual vmcnt ---
template <int I, int C0, int DEPTH, bool SC0, bool SC1>
__device__ __forceinline__ void stg_issue(u32x4 (&ring)[DEPTH],
    const u16* b0, const u16* b1) {
  constexpr int OFF = (I < C0 ? I : I - C0) * 128;
  if constexpr (I < C0) {
    if constexpr (SC0)
      asm volatile("global_load_dwordx4 %0, %1, off offset:%2 sc1"
                   : "=v"(ring[I % DEPTH]) : "v"(b0), "i"(OFF));
    else
      asm volatile("global_load_dwordx4 %0, %1, off offset:%2"
                   : "=v"(ring[I % DEPTH]) : "v"(b0), "i"(OFF));
  } else {
    if constexpr (SC1)
      asm volatile("global_load_dwordx4 %0, %1, off offset:%2 sc1"
                   : "=v"(ring[I % DEPTH]) : "v"(b1), "i"(OFF));
    else
      asm volatile("global_load_dwordx4 %0, %1, off offset:%2"
                   : "=v"(ring[I % DEPTH]) : "v"(b1), "i"(OFF));
  }
}

template <int I, int NPRE, int C0, int DEPTH, bool SC0, bool SC1>
__device__ __forceinline__ void stg_pre(u32x4 (&ring)[DEPTH],
    const u16* b0, const u16* b1) {
  if constexpr (I < NPRE) {
    stg_issue<I, C0, DEPTH, SC0, SC1>(ring, b0, b1);
    stg_pre<I + 1, NPRE, C0, DEPTH, SC0, SC1>(ring, b0, b1);
  }
}

// Write chunks [I, END) to LDS (waiting the ring), issuing replacements so
// ~DEPTH chunks stay in flight. vmcnt counts only ring loads here: h-stores
// drained at grid barrier, no other vmem between sub-tiles.
template <int I, int END, int NC, int C0, int DEPTH, bool SC0, bool SC1>
__device__ __forceinline__ void stg_span(u32x4 (&ring)[DEPTH],
    const u16* b0, const u16* b1, u16* lrow) {
  if constexpr (I < END) {
    constexpr int ISSUED = (I + DEPTH < NC) ? I + DEPTH : NC;
    constexpr int WAIT = ISSUED - I - 1;
    asm volatile("s_waitcnt vmcnt(%1)" : "+v"(ring[I % DEPTH]) : "i"(WAIT));
    *(u32x4*)(lrow + I * 64) = ring[I % DEPTH];   // ds_write_b128
    if constexpr (I + DEPTH < NC)
      stg_issue<I + DEPTH, C0, DEPTH, SC0, SC1>(ring, b0, b1);
    stg_span<I + 1, END, NC, C0, DEPTH, SC0, SC1>(ring, b0, b1, lrow);
  }
}

template <int NC, int C0, bool SC0, bool SC1>
__device__ __forceinline__ void stage(const u16* b0, const u16* b1, u16* lrow) {
  u32x4 ring[16];
  stg_pre<0, (NC < 16 ? NC : 16), C0, 16, SC0, SC1>(ring, b0, b1);
  stg_span<0, NC, NC, C0, 16, SC0, SC1>(ring, b0, b1, lrow);
}

// Fence-free tree barrier (R5-proven). bar lines 128B apart: [0]=root,
// [32*(1+g)]=group ctr, [32*(9+g)]=epoch. Monotone counters, no resets.
__device__ __forceinline__ void grid_barrier(unsigned* __restrict__ bar,
                                             int g, unsigned want) {
  asm volatile("s_waitcnt vmcnt(0)" ::: "memory");  // h stores acked at MALL
  __syncthreads();
  if (threadIdx.x == 0) {
    unsigned old = __hip_atomic_fetch_add(bar + 32 * (1 + g), 1u,
                                          __ATOMIC_RELAXED, __HIP_MEMORY_SCOPE_AGENT);
    if (old == 32u * want - 1u) {
      unsigned r = __hip_atomic_fetch_add(bar, 1u, __ATOMIC_RELAXED,
                                          __HIP_MEMORY_SCOPE_AGENT);
      if (r == 8u * want - 1u) {
#pragma unroll
        for (int i = 0; i < 8; ++i)
          __hip_atomic_store(bar + 32 * (9 + i), want, __ATOMIC_RELAXED,
                             __HIP_MEMORY_SCOPE_AGENT);
      }
    }
    while (__hip_atomic_load(bar + 32 * (9 + g), __ATOMIC_RELAXED,
                             __HIP_MEMORY_SCOPE_AGENT) < want)
      __builtin_amdgcn_s_sleep(1);
  }
  __syncthreads();
}

// One layer's persistent loop. NC = K/64 stage chunks, C0 = K0/64 (seg-0).
// Block: 32 batches (mhalf) x 64 gate-cols (strip); wave w = gate w, holds
// B-frags for its 16 units x full K in VGPRs (breg).
template <int NC, int C0, bool SC0, bool IS2>
__device__ __forceinline__ void run_layer(
    const u16* __restrict__ xbf, const u16* __restrict__ Wt,
    const u16* __restrict__ Ut, const float* __restrict__ bias,
    u16* __restrict__ h1r, u16* __restrict__ h2r, unsigned* __restrict__ bar,
    int strip, int mhalf, char* smem, int g) {
  constexpr int K = NC * 64;
  constexpr int P = K + 8;       // LDS row pitch (elements); +16B: bank stagger
  constexpr int NCH = NC * 2;    // MFMA k-chunks (32 elems each)
  constexpr int WCH = C0 * 2;    // k-chunks in W segment
  constexpr int NPS = NC / 4;    // stage chunks per sub-tile (8 / 6)
  constexpr int NCHS = NCH / 4;  // mfma k-chunks per sub-tile (16 / 12)
  u16* Alds = (u16*)smem;                       // [32][P]
  float* Zlds = (float*)(smem + LDS_Z_OFF);     // [32][68]
  const int tid = threadIdx.x;
  const int wave = tid >> 6, lane = tid & 63;
  const int quad = lane >> 4, l16 = lane & 15;

  // ---- weights -> registers (once; cached loads, init-time) ----
  bf16x8 breg[NCH];
  const int col = wave * 1024 + strip * 16 + l16;
#pragma unroll
  for (int ks = 0; ks < WCH; ++ks)
    breg[ks] = *(const bf16x8*)(Wt + (size_t)col * (C0 * 64) + ks * 32 + quad * 8);
#pragma unroll
  for (int ks = WCH; ks < NCH; ++ks)
    breg[ks] = *(const bf16x8*)(Ut + (size_t)col * 1024 + (ks - WCH) * 32 + quad * 8);

  // ---- epilogue coords: this thread owns (em,eu) and (em+16,eu) ----
  const int eu = tid & 15, em = tid >> 4;
  const float bz0 = bias[strip * 16 + eu];
  const float bz1 = bias[1024 + strip * 16 + eu];
  const float bz2 = bias[2048 + strip * 16 + eu];
  const float bz3 = bias[3072 + strip * 16 + eu];
  float cA = 0.f, cB = 0.f;

  // ---- staging coords: thread stages row sr, 16B lane l8 ----
  const int sr = tid >> 3, l8 = tid & 7;
  const int sb = mhalf * 32 + sr;               // global batch row
  u16* lrow = Alds + sr * P + l8 * 8;

  const u16* a0p = Alds + l16 * P + quad * 8;
  const u16* a1p = a0p + 16 * P;

#define MFMA_RNG(LO, HI)                                                     \
  {                                                                          \
    _Pragma("unroll")                                                        \
    for (int ks = (LO); ks < (HI); ++ks) {                                   \
      bf16x8 a0 = *(const bf16x8*)(a0p + ks * 32);                           \
      bf16x8 a1 = *(const bf16x8*)(a1p + ks * 32);                           \
      acc0 = __builtin_amdgcn_mfma_f32_16x16x32_bf16(a0, breg[ks], acc0, 0, 0, 0); \
      acc1 = __builtin_amdgcn_mfma_f32_16x16x32_bf16(a1, breg[ks], acc1, 0, 0, 0); \
    }                                                                        \
  }

  for (int s = 0; s <= 256; ++s) {
    const int t = IS2 ? (s - 1) : s;
    if (t >= 0 && t < 256) {
      const u16 *b0, *b1;
      if constexpr (IS2) {
        b0 = h1r + (size_t)(t & 1) * 65536 + (size_t)sb * 1024 + l8 * 8;
        b1 = h2r + (size_t)((t - 1) & 1) * 65536 + (size_t)sb * 1024 + l8 * 8;
      } else {
        b0 = xbf + ((size_t)sb * 256 + t) * 512 + l8 * 8;
        b1 = h1r + (size_t)((t - 1) & 1) * 65536 + (size_t)sb * 1024 + l8 * 8;
      }

      f32x4 acc0 = {0.f, 0.f, 0.f, 0.f}, acc1 = {0.f, 0.f, 0.f, 0.f};
      if (t > 0) {
        // ---- pipelined: MFMA(sub g) overlaps sub g+1..'s loads in flight.
        // Light barriers only (lgkmcnt + s_barrier): vmcnt stays counted, so
        // the ring's ~16 outstanding loads survive each barrier (T4).
        u32x4 ring[16];
        stg_pre<0, 16, C0, 16, SC0, true>(ring, b0, b1);
        stg_span<0, NPS, NC, C0, 16, SC0, true>(ring, b0, b1, lrow);
        sync_lds_only();
        MFMA_RNG(0, NCHS);
        stg_span<NPS, 2 * NPS, NC, C0, 16, SC0, true>(ring, b0, b1, lrow);
        sync_lds_only();
        MFMA_RNG(NCHS, 2 * NCHS);
        stg_span<2 * NPS, 3 * NPS, NC, C0, 16, SC0, true>(ring, b0, b1, lrow);
        sync_lds_only();
        MFMA_RNG(2 * NCHS, 3 * NCHS);
        stg_span<3 * NPS, NC, NC, C0, 16, SC0, true>(ring, b0, b1, lrow);
        sync_lds_only();
        MFMA_RNG(3 * NCHS, NCH);
      } else {                       // first step: recurrent state is zero
        stage<C0, C0, SC0, true>(b0, b0, lrow);
#pragma unroll
        for (int i = C0; i < NC; ++i)
          *(u32x4*)(lrow + i * 64) = (u32x4){0u, 0u, 0u, 0u};
        __syncthreads();
        MFMA_RNG(0, NCH);
      }

      // z exchange: C/D layout col=lane&15 (unit), row=quad*4+i (batch)
#pragma unroll
      for (int i = 0; i < 4; ++i) {
        Zlds[(quad * 4 + i) * 68 + wave * 16 + l16] = acc0[i];
        Zlds[(16 + quad * 4 + i) * 68 + wave * 16 + l16] = acc1[i];
      }
      __syncthreads();

      u16* hring = IS2 ? h2r : h1r;
      u16* hp = hring + (size_t)(t & 1) * 65536 +
                (size_t)(mhalf * 32) * 1024 + strip * 16 + eu;
      {
        float zi = Zlds[em * 68 + eu] + bz0;
        float zf = Zlds[em * 68 + 16 + eu] + bz1;
        float zg = Zlds[em * 68 + 32 + eu] + bz2;
        float zo = Zlds[em * 68 + 48 + eu] + bz3;
        float ig = 1.f / (1.f + __expf(-zi));
        float fg = 1.f / (1.f + __expf(-zf));
        float gg = 1.f - 2.f / (1.f + __expf(2.f * zg));
        float og = 1.f / (1.f + __expf(-zo));
        cA = fg * cA + ig * gg;
        float h = og * (1.f - 2.f / (1.f + __expf(2.f * cA)));
        store_h_sc1(hp + (size_t)em * 1024, (unsigned)f2bf(h));
      }
      {
        int m2 = em + 16;
        float zi = Zlds[m2 * 68 + eu] + bz0;
        float zf = Zlds[m2 * 68 + 16 + eu] + bz1;
        float zg = Zlds[m2 * 68 + 32 + eu] + bz2;
        float zo = Zlds[m2 * 68 + 48 + eu] + bz3;
        float ig = 1.f / (1.f + __expf(-zi));
        float fg = 1.f / (1.f + __expf(-zf));
        float gg = 1.f - 2.f / (1.f + __expf(2.f * zg));
        float og = 1.f / (1.f + __expf(-zo));
        cB = fg * cB + ig * gg;
        float h = og * (1.f - 2.f / (1.f + __expf(2.f * cB)));
        store_h_sc1(hp + (size_t)m2 * 1024, (unsigned)f2bf(h));
      }
    }
    if (s < 256) grid_barrier(bar, g, (unsigned)(s + 1));
  }
#undef MFMA_RNG
}

__global__ __launch_bounds__(256, 1) void lstm_persistent(
    const u16* __restrict__ xbf,   // [64][256][512] bf16
    const u16* __restrict__ W1t,   // [4096][512]
    const u16* __restrict__ U1t,   // [4096][1024]
    const float* __restrict__ b1,
    const u16* __restrict__ W2t,   // [4096][1024]
    const u16* __restrict__ U2t,   // [4096][1024]
    const float* __restrict__ b2,
    u16* __restrict__ h1r,         // [2][64][1024] bf16
    u16* __restrict__ h2r,         // [2][64][1024] bf16
    unsigned* __restrict__ bar) {
  extern __shared__ __align__(16) char smem[];
  const int blk = blockIdx.x;
  const bool is2 = blk >= 128;
  const int lb = is2 ? blk - 128 : blk;
  const int strip = lb >> 1;       // 64 col-strips of 16 units
  const int mhalf = lb & 1;        // batch half
  const int g = blk & 7;
  if (!is2)
    run_layer<24, 8, false, false>(xbf, W1t, U1t, b1, h1r, h2r, bar,
                                   strip, mhalf, smem, g);
  else
    run_layer<32, 16, true, true>(xbf, W2t, U2t, b2, h1r, h2r, bar,
                                  strip, mhalf, smem, g);
}

// out[64][512] = h2_last @ Wd + bd.  One wave per 16x16 tile, K=1024.
__global__ __launch_bounds__(64) void dense_kernel(
    const u16* __restrict__ h2,    // [64][1024] bf16
    const u16* __restrict__ Wdt,   // [512][1024] bf16
    const float* __restrict__ bd,
    float* __restrict__ out) {
  int mt = blockIdx.x >> 5;  // 0..3
  int nt = blockIdx.x & 31;  // 0..31
  int lane = threadIdx.x;
  int quad = lane >> 4, l16 = lane & 15;
  f32x4 acc = {0.f, 0.f, 0.f, 0.f};
  const u16* ap = h2 + (size_t)(mt * 16 + l16) * 1024 + quad * 8;
  const u16* bp = Wdt + (size_t)(nt * 16 + l16) * 1024 + quad * 8;
#pragma unroll
  for (int ks = 0; ks < 32; ++ks) {
    bf16x8 a = *reinterpret_cast<const bf16x8*>(ap + ks * 32);
    bf16x8 b = *reinterpret_cast<const bf16x8*>(bp + ks * 32);
    acc = __builtin_amdgcn_mfma_f32_16x16x32_bf16(a, b, acc, 0, 0, 0);
  }
  int colo = nt * 16 + l16;
  float bias = bd[colo];
#pragma unroll
  for (int i = 0; i < 4; ++i)
    out[(size_t)(mt * 16 + quad * 4 + i) * 512 + colo] = acc[i] + bias;
}

extern "C" void kernel_launch(void* const* d_in, const int* in_sizes, int n_in,
                              void* d_out, int out_size, void* d_ws, size_t ws_size,
                              hipStream_t stream) {
  const float* x  = (const float*)d_in[0];
  const float* W1 = (const float*)d_in[1];
  const float* U1 = (const float*)d_in[2];
  const float* b1 = (const float*)d_in[3];
  const float* W2 = (const float*)d_in[4];
  const float* U2 = (const float*)d_in[5];
  const float* b2 = (const float*)d_in[6];
  const float* Wd = (const float*)d_in[7];
  const float* bd = (const float*)d_in[8];
  float* out = (float*)d_out;

  char* p = (char*)d_ws;
  auto carve = [&](size_t bytes) -> char* {
    char* r = p;
    p += (bytes + 255) & ~(size_t)255;
    return r;
  };
  // ~45.5 MiB total (R2-proven budget; R1's 78 MiB overflowed ws)
  u16* W1t = (u16*)carve((size_t)4096 * 512 * 2);
  u16* U1t = (u16*)carve((size_t)4096 * 1024 * 2);
  u16* W2t = (u16*)carve((size_t)4096 * 1024 * 2);
  u16* U2t = (u16*)carve((size_t)4096 * 1024 * 2);
  u16* Wdt = (u16*)carve((size_t)512 * 1024 * 2);
  u16* xbf = (u16*)carve((size_t)64 * 256 * 512 * 2);
  u16* h1r = (u16*)carve((size_t)2 * 64 * 1024 * 2);
  u16* h2r = (u16*)carve((size_t)2 * 64 * 1024 * 2);
  unsigned* bar = (unsigned*)carve(1024 * 4);
  (void)ws_size; (void)in_sizes; (void)n_in; (void)out_size;

  transpose_to_bf16<<<dim3(128, 16), 256, 0, stream>>>(W1, W1t, 512, 4096);
  transpose_to_bf16<<<dim3(128, 32), 256, 0, stream>>>(U1, U1t, 1024, 4096);
  transpose_to_bf16<<<dim3(128, 32), 256, 0, stream>>>(W2, W2t, 1024, 4096);
  transpose_to_bf16<<<dim3(128, 32), 256, 0, stream>>>(U2, U2t, 1024, 4096);
  transpose_to_bf16<<<dim3(16, 32), 256, 0, stream>>>(Wd, Wdt, 1024, 512);
  convert_to_bf16<<<8192, 256, 0, stream>>>(x, xbf, 64 * 256 * 512 / 4);
  init_bar<<<1, 1024, 0, stream>>>(bar);

  hipFuncSetAttribute(reinterpret_cast<const void*>(lstm_persistent),
                      hipFuncAttributeMaxDynamicSharedMemorySize, LDS_TOTAL);
  lstm_persistent<<<256, 256, LDS_TOTAL, stream>>>(
      xbf, W1t, U1t, b1, W2t, U2t, b2, h1r, h2r, bar);

  dense_kernel<<<128, 64, 0, stream>>>(h2r + 65536, Wdt, bd, out);
}

// Round 3
// 1623.423 us; speedup vs baseline: 1.3032x; 1.3032x over previous
//
#include <hip/hip_runtime.h>

// ---------------------------------------------------------------------------
// 2-layer LSTM (B=64, T=256, D=512, H1=H2=1024) + dense head.
// R10: occupancy 1 -> 2 waves/SIMD. R8/R9 proved phase-splitting at 1
// wave/SIMD only adds lockstep skew (identical 2114/2115us for drain vs
// counted barriers) -> revert to R7's monolithic stage->sync->MFMA step.
// Structural fix instead: 512-thread blocks, 8 waves = (gate 0..3) x
// (K-half 0..1). Per-wave breg halves to 128 VGPR (layer2) -> true register
// residency under the 2-waves/SIMD 256-VGPR cap (__launch_bounds__(512,2)).
// K-half partials summed via doubled Zlds [2][32][68]. Each SIMD's 2 waves
// co-issue: ds_read/MALL latency hidden by the partner wave within each
// phase. Traffic (MALL A-stream, LDS reads) unchanged; ring depth 16->8.
// ---------------------------------------------------------------------------

typedef __bf16 bf16x8 __attribute__((ext_vector_type(8)));
typedef float f32x4 __attribute__((ext_vector_type(4)));
typedef unsigned int u32x4 __attribute__((ext_vector_type(4)));
typedef unsigned short u16;

#define LDS_Z_OFF 131584   // Alds worst: 32*(2048+8)*2 = 131584 B
#define LDS_TOTAL 148992   // + Zlds 2*32*68*4 = 17408 B

__device__ __forceinline__ u16 f2bf(float f) {
  unsigned u = __float_as_uint(f);
  unsigned r = (u + 0x7FFFu + ((u >> 16) & 1u)) >> 16;  // RNE (finite inputs)
  return (u16)r;
}

// in: fp32 [R][C] row-major  ->  out: bf16 [C][R] row-major (i.e. B^T layout)
__global__ __launch_bounds__(256) void transpose_to_bf16(
    const float* __restrict__ in, u16* __restrict__ out, int R, int C) {
  __shared__ float tile[32][33];
  int tx = threadIdx.x & 31, ty = threadIdx.x >> 5;  // 32 x 8
  int c0 = blockIdx.x * 32, r0 = blockIdx.y * 32;
#pragma unroll
  for (int i = 0; i < 4; ++i)
    tile[ty + i * 8][tx] = in[(size_t)(r0 + ty + i * 8) * C + (c0 + tx)];
  __syncthreads();
#pragma unroll
  for (int i = 0; i < 4; ++i)
    out[(size_t)(c0 + ty + i * 8) * R + (r0 + tx)] = f2bf(tile[tx][ty + i * 8]);
}

__global__ __launch_bounds__(256) void convert_to_bf16(
    const float* __restrict__ in, u16* __restrict__ out, int n4) {
  int i = blockIdx.x * 256 + threadIdx.x;
  if (i >= n4) return;
  float4 v = reinterpret_cast<const float4*>(in)[i];
  ushort4 o;
  o.x = f2bf(v.x); o.y = f2bf(v.y); o.z = f2bf(v.z); o.w = f2bf(v.w);
  reinterpret_cast<ushort4*>(out)[i] = o;
}

__global__ void init_bar(unsigned* __restrict__ bar) { bar[threadIdx.x] = 0u; }

__device__ __forceinline__ void store_h_sc1(u16* p, unsigned v) {
  asm volatile("global_store_short %0, %1, off sc1" :: "v"(p), "v"(v) : "memory");
}

// ---- A-staging: sc1/cached loads -> LDS via depth-8 ring, manual vmcnt ----
// Chunk = 32 rows x 256 B (one 16B slice per thread, 512 threads).
template <int I, int C0, int DEPTH, bool SC0, bool SC1>
__device__ __forceinline__ void stg_issue(u32x4 (&ring)[DEPTH],
    const u16* b0, const u16* b1) {
  constexpr int OFF = (I < C0 ? I : I - C0) * 256;
  if constexpr (I < C0) {
    if constexpr (SC0)
      asm volatile("global_load_dwordx4 %0, %1, off offset:%2 sc1"
                   : "=v"(ring[I % DEPTH]) : "v"(b0), "i"(OFF));
    else
      asm volatile("global_load_dwordx4 %0, %1, off offset:%2"
                   : "=v"(ring[I % DEPTH]) : "v"(b0), "i"(OFF));
  } else {
    if constexpr (SC1)
      asm volatile("global_load_dwordx4 %0, %1, off offset:%2 sc1"
                   : "=v"(ring[I % DEPTH]) : "v"(b1), "i"(OFF));
    else
      asm volatile("global_load_dwordx4 %0, %1, off offset:%2"
                   : "=v"(ring[I % DEPTH]) : "v"(b1), "i"(OFF));
  }
}

template <int I, int NPRE, int C0, int DEPTH, bool SC0, bool SC1>
__device__ __forceinline__ void stg_pre(u32x4 (&ring)[DEPTH],
    const u16* b0, const u16* b1) {
  if constexpr (I < NPRE) {
    stg_issue<I, C0, DEPTH, SC0, SC1>(ring, b0, b1);
    stg_pre<I + 1, NPRE, C0, DEPTH, SC0, SC1>(ring, b0, b1);
  }
}

template <int I, int NC, int C0, int DEPTH, bool SC0, bool SC1>
__device__ __forceinline__ void stg_main(u32x4 (&ring)[DEPTH],
    const u16* b0, const u16* b1, u16* lrow) {
  if constexpr (I < NC) {
    constexpr int ISSUED = (I + DEPTH < NC) ? I + DEPTH : NC;
    constexpr int WAIT = ISSUED - I - 1;
    asm volatile("s_waitcnt vmcnt(%1)" : "+v"(ring[I % DEPTH]) : "i"(WAIT));
    *(u32x4*)(lrow + I * 128) = ring[I % DEPTH];   // ds_write_b128
    if constexpr (I + DEPTH < NC)
      stg_issue<I + DEPTH, C0, DEPTH, SC0, SC1>(ring, b0, b1);
    stg_main<I + 1, NC, C0, DEPTH, SC0, SC1>(ring, b0, b1, lrow);
  }
}

template <int NC, int C0, bool SC0, bool SC1>
__device__ __forceinline__ void stage(const u16* b0, const u16* b1, u16* lrow) {
  u32x4 ring[8];
  stg_pre<0, (NC < 8 ? NC : 8), C0, 8, SC0, SC1>(ring, b0, b1);
  stg_main<0, NC, C0, 8, SC0, SC1>(ring, b0, b1, lrow);
}

// Fence-free tree barrier (R5-proven). bar lines 128B apart: [0]=root,
// [32*(1+g)]=group ctr, [32*(9+g)]=epoch. Monotone counters, no resets.
__device__ __forceinline__ void grid_barrier(unsigned* __restrict__ bar,
                                             int g, unsigned want) {
  asm volatile("s_waitcnt vmcnt(0)" ::: "memory");  // h stores acked at MALL
  __syncthreads();
  if (threadIdx.x == 0) {
    unsigned old = __hip_atomic_fetch_add(bar + 32 * (1 + g), 1u,
                                          __ATOMIC_RELAXED, __HIP_MEMORY_SCOPE_AGENT);
    if (old == 32u * want - 1u) {
      unsigned r = __hip_atomic_fetch_add(bar, 1u, __ATOMIC_RELAXED,
                                          __HIP_MEMORY_SCOPE_AGENT);
      if (r == 8u * want - 1u) {
#pragma unroll
        for (int i = 0; i < 8; ++i)
          __hip_atomic_store(bar + 32 * (9 + i), want, __ATOMIC_RELAXED,
                             __HIP_MEMORY_SCOPE_AGENT);
      }
    }
    while (__hip_atomic_load(bar + 32 * (9 + g), __ATOMIC_RELAXED,
                             __HIP_MEMORY_SCOPE_AGENT) < want)
      __builtin_amdgcn_s_sleep(1);
  }
  __syncthreads();
}

// One layer's persistent loop. Stage chunk = 256 B/row: NC = row_bytes/256,
// C0 = W-segment chunks. NCH = NC*4 MFMA k-chunks; wave (gate, kh) computes
// 16 cols over k-chunks [kh*NCH/2, (kh+1)*NCH/2), breg = NCH/2 frags.
template <int NC, int C0, bool SC0, bool IS2>
__device__ __forceinline__ void run_layer(
    const u16* __restrict__ xbf, const u16* __restrict__ Wt,
    const u16* __restrict__ Ut, const float* __restrict__ bias,
    u16* __restrict__ h1r, u16* __restrict__ h2r, unsigned* __restrict__ bar,
    int strip, int mhalf, char* smem, int g) {
  constexpr int KE = NC * 128;   // K (elements)
  constexpr int P = KE + 8;      // LDS row pitch (elements); +16B bank stagger
  constexpr int NCH = NC * 4;    // MFMA k-chunks (32 elems each)
  constexpr int WCH = C0 * 4;    // MFMA k-chunks in W segment
  constexpr int HALF = NCH / 2;  // k-chunks per wave
  u16* Alds = (u16*)smem;                       // [32][P]
  float* Zlds = (float*)(smem + LDS_Z_OFF);     // [2][32][68]
  const int tid = threadIdx.x;
  const int wave = tid >> 6, lane = tid & 63;
  const int gate = wave & 3, kh = wave >> 2;    // SIMD s: (gate s, kh 0/1)
  const int quad = lane >> 4, l16 = lane & 15;

  // ---- weights -> registers (once; 128 VGPR worst case -> resident) ----
  bf16x8 breg[HALF];
  const int col = gate * 1024 + strip * 16 + l16;
  const int kb = kh * HALF;
#pragma unroll
  for (int j = 0; j < HALF; ++j) {
    int ks = kb + j;
    if (ks < WCH)
      breg[j] = *(const bf16x8*)(Wt + (size_t)col * (WCH * 32) + ks * 32 + quad * 8);
    else
      breg[j] = *(const bf16x8*)(Ut + (size_t)col * 1024 + (ks - WCH) * 32 + quad * 8);
  }

  // ---- epilogue coords: thread owns one (batch em, unit eu) ----
  const int eu = tid & 15, em = tid >> 4;       // em 0..31
  const float bz0 = bias[strip * 16 + eu];
  const float bz1 = bias[1024 + strip * 16 + eu];
  const float bz2 = bias[2048 + strip * 16 + eu];
  const float bz3 = bias[3072 + strip * 16 + eu];
  float c = 0.f;

  // ---- staging coords: thread stages row sr, 16B slice l8 (16/row) ----
  const int sr = tid >> 4, l8 = tid & 15;
  const int sb = mhalf * 32 + sr;               // global batch row
  u16* lrow = Alds + sr * P + l8 * 8;

  const u16* a0p = Alds + l16 * P + quad * 8 + kb * 32;
  const u16* a1p = a0p + 16 * P;

  for (int s = 0; s <= 256; ++s) {
    const int t = IS2 ? (s - 1) : s;
    if (t >= 0 && t < 256) {
      const u16 *b0, *b1;
      if constexpr (IS2) {
        b0 = h1r + (size_t)(t & 1) * 65536 + (size_t)sb * 1024 + l8 * 8;
        b1 = h2r + (size_t)((t - 1) & 1) * 65536 + (size_t)sb * 1024 + l8 * 8;
      } else {
        b0 = xbf + ((size_t)sb * 256 + t) * 512 + l8 * 8;
        b1 = h1r + (size_t)((t - 1) & 1) * 65536 + (size_t)sb * 1024 + l8 * 8;
      }
      if (t > 0) {
        stage<NC, C0, SC0, true>(b0, b1, lrow);
      } else {                       // first step: recurrent state is zero
        stage<C0, C0, SC0, true>(b0, b0, lrow);
#pragma unroll
        for (int i = C0; i < NC; ++i)
          *(u32x4*)(lrow + i * 128) = (u32x4){0u, 0u, 0u, 0u};
      }
      __syncthreads();

      f32x4 acc0 = {0.f, 0.f, 0.f, 0.f}, acc1 = {0.f, 0.f, 0.f, 0.f};
#pragma unroll
      for (int j = 0; j < HALF; ++j) {
        bf16x8 a0 = *(const bf16x8*)(a0p + j * 32);
        bf16x8 a1 = *(const bf16x8*)(a1p + j * 32);
        acc0 = __builtin_amdgcn_mfma_f32_16x16x32_bf16(a0, breg[j], acc0, 0, 0, 0);
        acc1 = __builtin_amdgcn_mfma_f32_16x16x32_bf16(a1, breg[j], acc1, 0, 0, 0);
      }

      // z exchange: C/D layout col=lane&15 (unit), row=quad*4+i (batch);
      // kh slots summed in epilogue.
      float* zb = Zlds + kh * (32 * 68);
#pragma unroll
      for (int i = 0; i < 4; ++i) {
        zb[(quad * 4 + i) * 68 + gate * 16 + l16] = acc0[i];
        zb[(16 + quad * 4 + i) * 68 + gate * 16 + l16] = acc1[i];
      }
      __syncthreads();

      u16* hring = IS2 ? h2r : h1r;
      u16* hp = hring + (size_t)(t & 1) * 65536 +
                (size_t)(mhalf * 32 + em) * 1024 + strip * 16 + eu;
      {
        float zi = Zlds[em * 68 + eu]      + Zlds[(32 + em) * 68 + eu]      + bz0;
        float zf = Zlds[em * 68 + 16 + eu] + Zlds[(32 + em) * 68 + 16 + eu] + bz1;
        float zg = Zlds[em * 68 + 32 + eu] + Zlds[(32 + em) * 68 + 32 + eu] + bz2;
        float zo = Zlds[em * 68 + 48 + eu] + Zlds[(32 + em) * 68 + 48 + eu] + bz3;
        float ig = 1.f / (1.f + __expf(-zi));
        float fg = 1.f / (1.f + __expf(-zf));
        float gg = 1.f - 2.f / (1.f + __expf(2.f * zg));
        float og = 1.f / (1.f + __expf(-zo));
        c = fg * c + ig * gg;
        float h = og * (1.f - 2.f / (1.f + __expf(2.f * c)));
        store_h_sc1(hp, (unsigned)f2bf(h));
      }
    }
    if (s < 256) grid_barrier(bar, g, (unsigned)(s + 1));
  }
}

__global__ __launch_bounds__(512, 2) void lstm_persistent(
    const u16* __restrict__ xbf,   // [64][256][512] bf16
    const u16* __restrict__ W1t,   // [4096][512]
    const u16* __restrict__ U1t,   // [4096][1024]
    const float* __restrict__ b1,
    const u16* __restrict__ W2t,   // [4096][1024]
    const u16* __restrict__ U2t,   // [4096][1024]
    const float* __restrict__ b2,
    u16* __restrict__ h1r,         // [2][64][1024] bf16
    u16* __restrict__ h2r,         // [2][64][1024] bf16
    unsigned* __restrict__ bar) {
  extern __shared__ __align__(16) char smem[];
  const int blk = blockIdx.x;
  const bool is2 = blk >= 128;
  const int lb = is2 ? blk - 128 : blk;
  const int strip = lb >> 1;       // 64 col-strips of 16 units
  const int mhalf = lb & 1;        // batch half
  const int g = blk & 7;
  if (!is2)
    run_layer<12, 4, false, false>(xbf, W1t, U1t, b1, h1r, h2r, bar,
                                   strip, mhalf, smem, g);
  else
    run_layer<16, 8, true, true>(xbf, W2t, U2t, b2, h1r, h2r, bar,
                                 strip, mhalf, smem, g);
}

// out[64][512] = h2_last @ Wd + bd.  One wave per 16x16 tile, K=1024.
__global__ __launch_bounds__(64) void dense_kernel(
    const u16* __restrict__ h2,    // [64][1024] bf16
    const u16* __restrict__ Wdt,   // [512][1024] bf16
    const float* __restrict__ bd,
    float* __restrict__ out) {
  int mt = blockIdx.x >> 5;  // 0..3
  int nt = blockIdx.x & 31;  // 0..31
  int lane = threadIdx.x;
  int quad = lane >> 4, l16 = lane & 15;
  f32x4 acc = {0.f, 0.f, 0.f, 0.f};
  const u16* ap = h2 + (size_t)(mt * 16 + l16) * 1024 + quad * 8;
  const u16* bp = Wdt + (size_t)(nt * 16 + l16) * 1024 + quad * 8;
#pragma unroll
  for (int ks = 0; ks < 32; ++ks) {
    bf16x8 a = *reinterpret_cast<const bf16x8*>(ap + ks * 32);
    bf16x8 b = *reinterpret_cast<const bf16x8*>(bp + ks * 32);
    acc = __builtin_amdgcn_mfma_f32_16x16x32_bf16(a, b, acc, 0, 0, 0);
  }
  int colo = nt * 16 + l16;
  float bias = bd[colo];
#pragma unroll
  for (int i = 0; i < 4; ++i)
    out[(size_t)(mt * 16 + quad * 4 + i) * 512 + colo] = acc[i] + bias;
}

extern "C" void kernel_launch(void* const* d_in, const int* in_sizes, int n_in,
                              void* d_out, int out_size, void* d_ws, size_t ws_size,
                              hipStream_t stream) {
  const float* x  = (const float*)d_in[0];
  const float* W1 = (const float*)d_in[1];
  const float* U1 = (const float*)d_in[2];
  const float* b1 = (const float*)d_in[3];
  const float* W2 = (const float*)d_in[4];
  const float* U2 = (const float*)d_in[5];
  const float* b2 = (const float*)d_in[6];
  const float* Wd = (const float*)d_in[7];
  const float* bd = (const float*)d_in[8];
  float* out = (float*)d_out;

  char* p = (char*)d_ws;
  auto carve = [&](size_t bytes) -> char* {
    char* r = p;
    p += (bytes + 255) & ~(size_t)255;
    return r;
  };
  // ~45.5 MiB total (R2-proven budget; R1's 78 MiB overflowed ws)
  u16* W1t = (u16*)carve((size_t)4096 * 512 * 2);
  u16* U1t = (u16*)carve((size_t)4096 * 1024 * 2);
  u16* W2t = (u16*)carve((size_t)4096 * 1024 * 2);
  u16* U2t = (u16*)carve((size_t)4096 * 1024 * 2);
  u16* Wdt = (u16*)carve((size_t)512 * 1024 * 2);
  u16* xbf = (u16*)carve((size_t)64 * 256 * 512 * 2);
  u16* h1r = (u16*)carve((size_t)2 * 64 * 1024 * 2);
  u16* h2r = (u16*)carve((size_t)2 * 64 * 1024 * 2);
  unsigned* bar = (unsigned*)carve(1024 * 4);
  (void)ws_size; (void)in_sizes; (void)n_in; (void)out_size;

  transpose_to_bf16<<<dim3(128, 16), 256, 0, stream>>>(W1, W1t, 512, 4096);
  transpose_to_bf16<<<dim3(128, 32), 256, 0, stream>>>(U1, U1t, 1024, 4096);
  transpose_to_bf16<<<dim3(128, 32), 256, 0, stream>>>(W2, W2t, 1024, 4096);
  transpose_to_bf16<<<dim3(128, 32), 256, 0, stream>>>(U2, U2t, 1024, 4096);
  transpose_to_bf16<<<dim3(16, 32), 256, 0, stream>>>(Wd, Wdt, 1024, 512);
  convert_to_bf16<<<8192, 256, 0, stream>>>(x, xbf, 64 * 256 * 512 / 4);
  init_bar<<<1, 1024, 0, stream>>>(bar);

  hipFuncSetAttribute(reinterpret_cast<const void*>(lstm_persistent),
                      hipFuncAttributeMaxDynamicSharedMemorySize, LDS_TOTAL);
  lstm_persistent<<<256, 512, LDS_TOTAL, stream>>>(
      xbf, W1t, U1t, b1, W2t, U2t, b2, h1r, h2r, bar);

  dense_kernel<<<128, 64, 0, stream>>>(h2r + 65536, Wdt, bd, out);
}

// Round 4
// 1467.754 us; speedup vs baseline: 1.4414x; 1.1061x over previous
//
#include <hip/hip_runtime.h>

// ---------------------------------------------------------------------------
// 2-layer LSTM (B=64, T=256, D=512, H1=H2=1024) + dense head.
// R11: halve LDS A-read traffic via A-frag reuse across a gate PAIR.
// R10 (1554us lstm): occupancy 2 waves/SIMD confirmed (24.4%) but near-null
// -> phases are throughput-bound (MALL stage ~2.8us, LDS-read compute
// ~2.5us, barrier ~1.2us), not latency-bound. Compute reads the A-tile 4x
// redundantly (4 gate-waves x same frags; read:MFMA = 1:1). Fix: wave =
// (gate-pair cp, K-quarter kq): breg holds 2 gates x K/4 (<=128 VGPR), each
// a0/a1 ds_read feeds 2 MFMAs -> LDS reads 512->256 KB/CU/step. The 4
// kq-partials fold through the existing Zlds[2] buffers: kq<2 store, sync,
// kq>=2 read-add-write, sync (one extra block barrier). Stage/ring/grid
// barrier/epilogue byte-identical to R10.
// ---------------------------------------------------------------------------

typedef __bf16 bf16x8 __attribute__((ext_vector_type(8)));
typedef float f32x4 __attribute__((ext_vector_type(4)));
typedef unsigned int u32x4 __attribute__((ext_vector_type(4)));
typedef unsigned short u16;

#define LDS_Z_OFF 131584   // Alds worst: 32*(2048+8)*2 = 131584 B
#define LDS_TOTAL 148992   // + Zlds 2*32*68*4 = 17408 B

__device__ __forceinline__ u16 f2bf(float f) {
  unsigned u = __float_as_uint(f);
  unsigned r = (u + 0x7FFFu + ((u >> 16) & 1u)) >> 16;  // RNE (finite inputs)
  return (u16)r;
}

// in: fp32 [R][C] row-major  ->  out: bf16 [C][R] row-major (i.e. B^T layout)
__global__ __launch_bounds__(256) void transpose_to_bf16(
    const float* __restrict__ in, u16* __restrict__ out, int R, int C) {
  __shared__ float tile[32][33];
  int tx = threadIdx.x & 31, ty = threadIdx.x >> 5;  // 32 x 8
  int c0 = blockIdx.x * 32, r0 = blockIdx.y * 32;
#pragma unroll
  for (int i = 0; i < 4; ++i)
    tile[ty + i * 8][tx] = in[(size_t)(r0 + ty + i * 8) * C + (c0 + tx)];
  __syncthreads();
#pragma unroll
  for (int i = 0; i < 4; ++i)
    out[(size_t)(c0 + ty + i * 8) * R + (r0 + tx)] = f2bf(tile[tx][ty + i * 8]);
}

__global__ __launch_bounds__(256) void convert_to_bf16(
    const float* __restrict__ in, u16* __restrict__ out, int n4) {
  int i = blockIdx.x * 256 + threadIdx.x;
  if (i >= n4) return;
  float4 v = reinterpret_cast<const float4*>(in)[i];
  ushort4 o;
  o.x = f2bf(v.x); o.y = f2bf(v.y); o.z = f2bf(v.z); o.w = f2bf(v.w);
  reinterpret_cast<ushort4*>(out)[i] = o;
}

__global__ void init_bar(unsigned* __restrict__ bar) { bar[threadIdx.x] = 0u; }

__device__ __forceinline__ void store_h_sc1(u16* p, unsigned v) {
  asm volatile("global_store_short %0, %1, off sc1" :: "v"(p), "v"(v) : "memory");
}

// ---- A-staging: sc1/cached loads -> LDS via depth-8 ring, manual vmcnt ----
// Chunk = 32 rows x 256 B (one 16B slice per thread, 512 threads).
template <int I, int C0, int DEPTH, bool SC0, bool SC1>
__device__ __forceinline__ void stg_issue(u32x4 (&ring)[DEPTH],
    const u16* b0, const u16* b1) {
  constexpr int OFF = (I < C0 ? I : I - C0) * 256;
  if constexpr (I < C0) {
    if constexpr (SC0)
      asm volatile("global_load_dwordx4 %0, %1, off offset:%2 sc1"
                   : "=v"(ring[I % DEPTH]) : "v"(b0), "i"(OFF));
    else
      asm volatile("global_load_dwordx4 %0, %1, off offset:%2"
                   : "=v"(ring[I % DEPTH]) : "v"(b0), "i"(OFF));
  } else {
    if constexpr (SC1)
      asm volatile("global_load_dwordx4 %0, %1, off offset:%2 sc1"
                   : "=v"(ring[I % DEPTH]) : "v"(b1), "i"(OFF));
    else
      asm volatile("global_load_dwordx4 %0, %1, off offset:%2"
                   : "=v"(ring[I % DEPTH]) : "v"(b1), "i"(OFF));
  }
}

template <int I, int NPRE, int C0, int DEPTH, bool SC0, bool SC1>
__device__ __forceinline__ void stg_pre(u32x4 (&ring)[DEPTH],
    const u16* b0, const u16* b1) {
  if constexpr (I < NPRE) {
    stg_issue<I, C0, DEPTH, SC0, SC1>(ring, b0, b1);
    stg_pre<I + 1, NPRE, C0, DEPTH, SC0, SC1>(ring, b0, b1);
  }
}

template <int I, int NC, int C0, int DEPTH, bool SC0, bool SC1>
__device__ __forceinline__ void stg_main(u32x4 (&ring)[DEPTH],
    const u16* b0, const u16* b1, u16* lrow) {
  if constexpr (I < NC) {
    constexpr int ISSUED = (I + DEPTH < NC) ? I + DEPTH : NC;
    constexpr int WAIT = ISSUED - I - 1;
    asm volatile("s_waitcnt vmcnt(%1)" : "+v"(ring[I % DEPTH]) : "i"(WAIT));
    *(u32x4*)(lrow + I * 128) = ring[I % DEPTH];   // ds_write_b128
    if constexpr (I + DEPTH < NC)
      stg_issue<I + DEPTH, C0, DEPTH, SC0, SC1>(ring, b0, b1);
    stg_main<I + 1, NC, C0, DEPTH, SC0, SC1>(ring, b0, b1, lrow);
  }
}

template <int NC, int C0, bool SC0, bool SC1>
__device__ __forceinline__ void stage(const u16* b0, const u16* b1, u16* lrow) {
  u32x4 ring[8];
  stg_pre<0, (NC < 8 ? NC : 8), C0, 8, SC0, SC1>(ring, b0, b1);
  stg_main<0, NC, C0, 8, SC0, SC1>(ring, b0, b1, lrow);
}

// Fence-free tree barrier (R5-proven). bar lines 128B apart: [0]=root,
// [32*(1+g)]=group ctr, [32*(9+g)]=epoch. Monotone counters, no resets.
__device__ __forceinline__ void grid_barrier(unsigned* __restrict__ bar,
                                             int g, unsigned want) {
  asm volatile("s_waitcnt vmcnt(0)" ::: "memory");  // h stores acked at MALL
  __syncthreads();
  if (threadIdx.x == 0) {
    unsigned old = __hip_atomic_fetch_add(bar + 32 * (1 + g), 1u,
                                          __ATOMIC_RELAXED, __HIP_MEMORY_SCOPE_AGENT);
    if (old == 32u * want - 1u) {
      unsigned r = __hip_atomic_fetch_add(bar, 1u, __ATOMIC_RELAXED,
                                          __HIP_MEMORY_SCOPE_AGENT);
      if (r == 8u * want - 1u) {
#pragma unroll
        for (int i = 0; i < 8; ++i)
          __hip_atomic_store(bar + 32 * (9 + i), want, __ATOMIC_RELAXED,
                             __HIP_MEMORY_SCOPE_AGENT);
      }
    }
    while (__hip_atomic_load(bar + 32 * (9 + g), __ATOMIC_RELAXED,
                             __HIP_MEMORY_SCOPE_AGENT) < want)
      __builtin_amdgcn_s_sleep(1);
  }
  __syncthreads();
}

// One layer's persistent loop. Stage chunk = 256 B/row: NC = row_bytes/256.
// MFMA k-chunks NCH = NC*4; wave (cp, kq) = (gate-pair, K-quarter) holds
// breg[2][NC] (gates 2cp,2cp+1; k-chunks kq*NC..kq*NC+NC-1). Each a0/a1
// ds_read feeds 2 MFMAs. kq-partials: pairwise fold into Zlds[2] buffers.
template <int NC, int C0, bool SC0, bool IS2>
__device__ __forceinline__ void run_layer(
    const u16* __restrict__ xbf, const u16* __restrict__ Wt,
    const u16* __restrict__ Ut, const float* __restrict__ bias,
    u16* __restrict__ h1r, u16* __restrict__ h2r, unsigned* __restrict__ bar,
    int strip, int mhalf, char* smem, int g) {
  constexpr int KE = NC * 128;   // K (elements)
  constexpr int P = KE + 8;      // LDS row pitch (elements); +16B bank stagger
  constexpr int WCH = C0 * 4;    // MFMA k-chunks in W segment
  u16* Alds = (u16*)smem;                       // [32][P]
  float* Zlds = (float*)(smem + LDS_Z_OFF);     // [2][32][68]
  const int tid = threadIdx.x;
  const int wave = tid >> 6, lane = tid & 63;
  const int cp = wave & 1, kq = wave >> 1;      // gate-pair, K-quarter
  const int quad = lane >> 4, l16 = lane & 15;

  // ---- weights -> registers (once; breg[2][NC] <= 128 VGPR, resident) ----
  bf16x8 breg[2][NC];
#pragma unroll
  for (int gi = 0; gi < 2; ++gi) {
    const int col = (2 * cp + gi) * 1024 + strip * 16 + l16;
#pragma unroll
    for (int j = 0; j < NC; ++j) {
      const int ks = kq * NC + j;
      breg[gi][j] = (ks < WCH)
        ? *(const bf16x8*)(Wt + (size_t)col * (C0 * 128) + ks * 32 + quad * 8)
        : *(const bf16x8*)(Ut + (size_t)col * 1024 + (ks - WCH) * 32 + quad * 8);
    }
  }

  // ---- epilogue coords: thread owns one (batch em, unit eu) ----
  const int eu = tid & 15, em = tid >> 4;       // em 0..31
  const float bz0 = bias[strip * 16 + eu];
  const float bz1 = bias[1024 + strip * 16 + eu];
  const float bz2 = bias[2048 + strip * 16 + eu];
  const float bz3 = bias[3072 + strip * 16 + eu];
  float c = 0.f;

  // ---- staging coords: thread stages row sr, 16B slice l8 (16/row) ----
  const int sr = tid >> 4, l8 = tid & 15;
  const int sb = mhalf * 32 + sr;               // global batch row
  u16* lrow = Alds + sr * P + l8 * 8;

  const u16* a0p = Alds + l16 * P + quad * 8 + kq * (NC * 32);
  const u16* a1p = a0p + 16 * P;

  // Z columns this wave produces: gates 2cp (+0) and 2cp+1 (+16)
  const int zc0 = cp * 32 + l16, zc1 = zc0 + 16;
  float* zb = Zlds + (kq & 1) * (32 * 68);

  for (int s = 0; s <= 256; ++s) {
    const int t = IS2 ? (s - 1) : s;
    if (t >= 0 && t < 256) {
      const u16 *b0, *b1;
      if constexpr (IS2) {
        b0 = h1r + (size_t)(t & 1) * 65536 + (size_t)sb * 1024 + l8 * 8;
        b1 = h2r + (size_t)((t - 1) & 1) * 65536 + (size_t)sb * 1024 + l8 * 8;
      } else {
        b0 = xbf + ((size_t)sb * 256 + t) * 512 + l8 * 8;
        b1 = h1r + (size_t)((t - 1) & 1) * 65536 + (size_t)sb * 1024 + l8 * 8;
      }
      if (t > 0) {
        stage<NC, C0, SC0, true>(b0, b1, lrow);
      } else {                       // first step: recurrent state is zero
        stage<C0, C0, SC0, true>(b0, b0, lrow);
#pragma unroll
        for (int i = C0; i < NC; ++i)
          *(u32x4*)(lrow + i * 128) = (u32x4){0u, 0u, 0u, 0u};
      }
      __syncthreads();

      // acc[gi][mh]: gi = gate-in-pair, mh = m-half (rows mh*16..mh*16+15)
      f32x4 acc00 = {0.f, 0.f, 0.f, 0.f}, acc10 = {0.f, 0.f, 0.f, 0.f};
      f32x4 acc01 = {0.f, 0.f, 0.f, 0.f}, acc11 = {0.f, 0.f, 0.f, 0.f};
#pragma unroll
      for (int j = 0; j < NC; ++j) {
        bf16x8 a0 = *(const bf16x8*)(a0p + j * 32);
        bf16x8 a1 = *(const bf16x8*)(a1p + j * 32);
        acc00 = __builtin_amdgcn_mfma_f32_16x16x32_bf16(a0, breg[0][j], acc00, 0, 0, 0);
        acc10 = __builtin_amdgcn_mfma_f32_16x16x32_bf16(a1, breg[0][j], acc10, 0, 0, 0);
        acc01 = __builtin_amdgcn_mfma_f32_16x16x32_bf16(a0, breg[1][j], acc01, 0, 0, 0);
        acc11 = __builtin_amdgcn_mfma_f32_16x16x32_bf16(a1, breg[1][j], acc11, 0, 0, 0);
      }

      // kq-partial fold: kq<2 store into buffer (kq&1); sync; kq>=2 add into
      // same buffer; sync. C/D layout: col=lane&15 (unit), row=quad*4+i.
      if (kq < 2) {
#pragma unroll
        for (int i = 0; i < 4; ++i) {
          zb[(quad * 4 + i) * 68 + zc0] = acc00[i];
          zb[(16 + quad * 4 + i) * 68 + zc0] = acc10[i];
          zb[(quad * 4 + i) * 68 + zc1] = acc01[i];
          zb[(16 + quad * 4 + i) * 68 + zc1] = acc11[i];
        }
      }
      __syncthreads();
      if (kq >= 2) {
#pragma unroll
        for (int i = 0; i < 4; ++i) {
          zb[(quad * 4 + i) * 68 + zc0] += acc00[i];
          zb[(16 + quad * 4 + i) * 68 + zc0] += acc10[i];
          zb[(quad * 4 + i) * 68 + zc1] += acc01[i];
          zb[(16 + quad * 4 + i) * 68 + zc1] += acc11[i];
        }
      }
      __syncthreads();

      u16* hring = IS2 ? h2r : h1r;
      u16* hp = hring + (size_t)(t & 1) * 65536 +
                (size_t)(mhalf * 32 + em) * 1024 + strip * 16 + eu;
      {
        float zi = Zlds[em * 68 + eu]      + Zlds[(32 + em) * 68 + eu]      + bz0;
        float zf = Zlds[em * 68 + 16 + eu] + Zlds[(32 + em) * 68 + 16 + eu] + bz1;
        float zg = Zlds[em * 68 + 32 + eu] + Zlds[(32 + em) * 68 + 32 + eu] + bz2;
        float zo = Zlds[em * 68 + 48 + eu] + Zlds[(32 + em) * 68 + 48 + eu] + bz3;
        float ig = 1.f / (1.f + __expf(-zi));
        float fg = 1.f / (1.f + __expf(-zf));
        float gg = 1.f - 2.f / (1.f + __expf(2.f * zg));
        float og = 1.f / (1.f + __expf(-zo));
        c = fg * c + ig * gg;
        float h = og * (1.f - 2.f / (1.f + __expf(2.f * c)));
        store_h_sc1(hp, (unsigned)f2bf(h));
      }
    }
    if (s < 256) grid_barrier(bar, g, (unsigned)(s + 1));
  }
}

__global__ __launch_bounds__(512, 2) void lstm_persistent(
    const u16* __restrict__ xbf,   // [64][256][512] bf16
    const u16* __restrict__ W1t,   // [4096][512]
    const u16* __restrict__ U1t,   // [4096][1024]
    const float* __restrict__ b1,
    const u16* __restrict__ W2t,   // [4096][1024]
    const u16* __restrict__ U2t,   // [4096][1024]
    const float* __restrict__ b2,
    u16* __restrict__ h1r,         // [2][64][1024] bf16
    u16* __restrict__ h2r,         // [2][64][1024] bf16
    unsigned* __restrict__ bar) {
  extern __shared__ __align__(16) char smem[];
  const int blk = blockIdx.x;
  const bool is2 = blk >= 128;
  const int lb = is2 ? blk - 128 : blk;
  const int strip = lb >> 1;       // 64 col-strips of 16 units
  const int mhalf = lb & 1;        // batch half
  const int g = blk & 7;
  if (!is2)
    run_layer<12, 4, false, false>(xbf, W1t, U1t, b1, h1r, h2r, bar,
                                   strip, mhalf, smem, g);
  else
    run_layer<16, 8, true, true>(xbf, W2t, U2t, b2, h1r, h2r, bar,
                                 strip, mhalf, smem, g);
}

// out[64][512] = h2_last @ Wd + bd.  One wave per 16x16 tile, K=1024.
__global__ __launch_bounds__(64) void dense_kernel(
    const u16* __restrict__ h2,    // [64][1024] bf16
    const u16* __restrict__ Wdt,   // [512][1024] bf16
    const float* __restrict__ bd,
    float* __restrict__ out) {
  int mt = blockIdx.x >> 5;  // 0..3
  int nt = blockIdx.x & 31;  // 0..31
  int lane = threadIdx.x;
  int quad = lane >> 4, l16 = lane & 15;
  f32x4 acc = {0.f, 0.f, 0.f, 0.f};
  const u16* ap = h2 + (size_t)(mt * 16 + l16) * 1024 + quad * 8;
  const u16* bp = Wdt + (size_t)(nt * 16 + l16) * 1024 + quad * 8;
#pragma unroll
  for (int ks = 0; ks < 32; ++ks) {
    bf16x8 a = *reinterpret_cast<const bf16x8*>(ap + ks * 32);
    bf16x8 b = *reinterpret_cast<const bf16x8*>(bp + ks * 32);
    acc = __builtin_amdgcn_mfma_f32_16x16x32_bf16(a, b, acc, 0, 0, 0);
  }
  int colo = nt * 16 + l16;
  float bias = bd[colo];
#pragma unroll
  for (int i = 0; i < 4; ++i)
    out[(size_t)(mt * 16 + quad * 4 + i) * 512 + colo] = acc[i] + bias;
}

extern "C" void kernel_launch(void* const* d_in, const int* in_sizes, int n_in,
                              void* d_out, int out_size, void* d_ws, size_t ws_size,
                              hipStream_t stream) {
  const float* x  = (const float*)d_in[0];
  const float* W1 = (const float*)d_in[1];
  const float* U1 = (const float*)d_in[2];
  const float* b1 = (const float*)d_in[3];
  const float* W2 = (const float*)d_in[4];
  const float* U2 = (const float*)d_in[5];
  const float* b2 = (const float*)d_in[6];
  const float* Wd = (const float*)d_in[7];
  const float* bd = (const float*)d_in[8];
  float* out = (float*)d_out;

  char* p = (char*)d_ws;
  auto carve = [&](size_t bytes) -> char* {
    char* r = p;
    p += (bytes + 255) & ~(size_t)255;
    return r;
  };
  // ~45.5 MiB total (R2-proven budget; R1's 78 MiB overflowed ws)
  u16* W1t = (u16*)carve((size_t)4096 * 512 * 2);
  u16* U1t = (u16*)carve((size_t)4096 * 1024 * 2);
  u16* W2t = (u16*)carve((size_t)4096 * 1024 * 2);
  u16* U2t = (u16*)carve((size_t)4096 * 1024 * 2);
  u16* Wdt = (u16*)carve((size_t)512 * 1024 * 2);
  u16* xbf = (u16*)carve((size_t)64 * 256 * 512 * 2);
  u16* h1r = (u16*)carve((size_t)2 * 64 * 1024 * 2);
  u16* h2r = (u16*)carve((size_t)2 * 64 * 1024 * 2);
  unsigned* bar = (unsigned*)carve(1024 * 4);
  (void)ws_size; (void)in_sizes; (void)n_in; (void)out_size;

  transpose_to_bf16<<<dim3(128, 16), 256, 0, stream>>>(W1, W1t, 512, 4096);
  transpose_to_bf16<<<dim3(128, 32), 256, 0, stream>>>(U1, U1t, 1024, 4096);
  transpose_to_bf16<<<dim3(128, 32), 256, 0, stream>>>(W2, W2t, 1024, 4096);
  transpose_to_bf16<<<dim3(128, 32), 256, 0, stream>>>(U2, U2t, 1024, 4096);
  transpose_to_bf16<<<dim3(16, 32), 256, 0, stream>>>(Wd, Wdt, 1024, 512);
  convert_to_bf16<<<8192, 256, 0, stream>>>(x, xbf, 64 * 256 * 512 / 4);
  init_bar<<<1, 1024, 0, stream>>>(bar);

  hipFuncSetAttribute(reinterpret_cast<const void*>(lstm_persistent),
                      hipFuncAttributeMaxDynamicSharedMemorySize, LDS_TOTAL);
  lstm_persistent<<<256, 512, LDS_TOTAL, stream>>>(
      xbf, W1t, U1t, b1, W2t, U2t, b2, h1r, h2r, bar);

  dense_kernel<<<128, 64, 0, stream>>>(h2r + 65536, Wdt, bd, out);
}